// Round 11
// baseline (486.675 us; speedup 1.0000x reference)
//
#include <hip/hip_runtime.h>
#include <math.h>

#define ALPHA 0.2f
#define LOG2E 1.44269504088896f

constexpr int FEATS = 256;
constexpr int HEADS = 8;

typedef unsigned short u16;
typedef __attribute__((ext_vector_type(8))) short bf16x8;
typedef __attribute__((ext_vector_type(4))) float f32x4;

__device__ __forceinline__ u16 f2b(float f) {            // RNE
    unsigned u = __float_as_uint(f);
    u += 0x7FFF + ((u >> 16) & 1);
    return (u16)(u >> 16);
}
__device__ __forceinline__ float b2f(u16 x) {
    return __uint_as_float(((unsigned)x) << 16);
}
__device__ __forceinline__ unsigned pk2(float lo, float hi) {
    return __builtin_amdgcn_perm(__float_as_uint(hi), __float_as_uint(lo), 0x07060302u);
}
__device__ __forceinline__ void gload16(const void* g, void* l) {
    __builtin_amdgcn_global_load_lds(
        (const __attribute__((address_space(1))) unsigned int*)g,
        (__attribute__((address_space(3))) unsigned int*)l, 16, 0, 0);
}
__device__ __forceinline__ float rsum16(float v) {
    v += __shfl_xor(v, 1); v += __shfl_xor(v, 2);
    v += __shfl_xor(v, 4); v += __shfl_xor(v, 8);
    return v;
}

// ---------- prep (weight convert/reorder) || count3 (CSR histogram) ----------
__global__ void prep_count_kernel(
    const float* __restrict__ W_gat, const float* __restrict__ W_x,
    const float* __restrict__ W_ih, const float* __restrict__ W_hh,
    u16* __restrict__ Bgat, u16* __restrict__ Bx,
    u16* __restrict__ Bihr, u16* __restrict__ Bhhr,
    const int* __restrict__ d0, const int* __restrict__ d1,
    const int* __restrict__ d2, int* __restrict__ cnt, int E, int N) {
    int b = blockIdx.x;
    if (b < 2048) {
        int i = b * 256 + threadIdx.x;   // [0, 524288)
        if (i < 131072) {
            int j = i & 65535;
            int n = j >> 8, f = j & 255;
            int h2 = n >> 5, d = n & 31;
            const float* W = (i < 65536) ? W_gat : W_x;
            u16* Bt = (i < 65536) ? Bgat : Bx;
            Bt[j] = f2b(W[(h2 * 256 + f) * 32 + d]);
        } else {
            int x = i - 131072;
            int lin = (x < 196608) ? x : x - 196608;
            int c = lin >> 8, k = lin & 255;
            int q = c / 48, rr = c - q * 48;
            int g = rr >> 4, jl = rr & 15;
            int orig = (g * 256 + q * 16 + jl) * 256 + k;
            if (x < 196608) Bihr[lin] = f2b(W_ih[orig]);
            else            Bhhr[lin] = f2b(W_hh[orig]);
        }
    } else {
        int i = (b - 2048) * 256 + threadIdx.x;
        if (i >= 3 * E) return;
        if (i < E) atomicAdd(&cnt[d0[i]], 1);
        else if (i < 2 * E) atomicAdd(&cnt[N + d1[i - E]], 1);
        else atomicAdd(&cnt[2 * N + d2[i - 2 * E]], 1);
    }
}

// ---------- scan (1024 elems/block, 2-level) ----------
__global__ void scan1_kernel(const int* __restrict__ cnt, int* __restrict__ off,
                             int* __restrict__ blksum, int n) {
    __shared__ int tmp[256];
    int t = threadIdx.x;
    int base = blockIdx.x * 1024 + t * 4;
    int v[4];
#pragma unroll
    for (int k = 0; k < 4; ++k) v[k] = (base + k < n) ? cnt[base + k] : 0;
    int s = v[0] + v[1] + v[2] + v[3];
    tmp[t] = s;
    __syncthreads();
    for (int st = 1; st < 256; st <<= 1) {
        int add = (t >= st) ? tmp[t - st] : 0;
        __syncthreads();
        tmp[t] += add;
        __syncthreads();
    }
    int ex = tmp[t] - s;
#pragma unroll
    for (int k = 0; k < 4; ++k) {
        if (base + k < n) off[base + k] = ex;
        ex += v[k];
    }
    if (t == 255) blksum[blockIdx.x] = tmp[255];
}
__global__ void scan2_kernel(int* __restrict__ blksum, int nb) {
    __shared__ int tmp[256];
    int t = threadIdx.x;
    int v = (t < nb) ? blksum[t] : 0;
    tmp[t] = v;
    __syncthreads();
    for (int s = 1; s < 256; s <<= 1) {
        int add = (t >= s) ? tmp[t - s] : 0;
        __syncthreads();
        tmp[t] += add;
        __syncthreads();
    }
    if (t < nb) blksum[t] = tmp[t] - v;
}
__global__ void scan3_kernel(int* __restrict__ off, int* __restrict__ cur,
                             const int* __restrict__ blksum, int n) {
    int i = blockIdx.x * blockDim.x + threadIdx.x;
    if (i < n) {
        int v = off[i] + blksum[i >> 10];
        off[i] = v;
        cur[i] = v;
    }
}

// ---------- fill3: dedicated kernel (0 LDS -> max occupancy) ----------
__global__ void fill3_kernel(const int* __restrict__ s0, const int* __restrict__ d0,
                             const int* __restrict__ s1, const int* __restrict__ d1,
                             const int* __restrict__ s2, const int* __restrict__ d2,
                             int* __restrict__ cur, int* __restrict__ srcs, int E, int N) {
    int i = blockIdx.x * blockDim.x + threadIdx.x;
    if (i >= 3 * E) return;
    int s, slot;
    if (i < E) { s = s0[i]; slot = d0[i]; }
    else if (i < 2 * E) { s = s1[i - E]; slot = N + d1[i - E]; }
    else { s = s2[i - 2 * E]; slot = 2 * N + d2[i - 2 * E]; }
    int p = atomicAdd(&cur[slot], 1);
    srcs[p] = s;
}

// ---------- proj4: 4-way projection GEMM + fused es/ed, BK=32 double-buffered --
// 8 waves, 128 rows x 256 cols per block. Prefetch next K-tile before compute.
__global__ __launch_bounds__(512, 4) void proj4_kernel(
    const float* __restrict__ A0, const float* __restrict__ A1,
    const float* __restrict__ A2, const float* __restrict__ A3,
    const u16* __restrict__ Bg, const u16* __restrict__ Bx,
    const float* __restrict__ bg, const float* __restrict__ bx,
    u16* __restrict__ C0, u16* __restrict__ C1,
    u16* __restrict__ C2, u16* __restrict__ C3,
    const float* __restrict__ as_g, const float* __restrict__ ad_g,
    const float* __restrict__ as_x, const float* __restrict__ ad_x,
    float* __restrict__ es1, float* __restrict__ ed1,
    float* __restrict__ esC, float* __restrict__ edD,
    float* __restrict__ esS,
    int M, int NB) {
    __shared__ char As_raw[2][16384];  // 128 rows x 32 f32 (8 x 16B units, XOR row&7)
    __shared__ char Bs_raw[2][16384];  // 256 rows x 32 bf16 (4 x 16B units, XOR (row>>1)&3)
    const int tid = threadIdx.x;
    const int lane = tid & 63;
    const int wid = tid >> 6;                 // 8 waves
    const int wr = wid >> 2, wc = wid & 3;    // 2 x 4
    const int seg = blockIdx.x / NB;
    const int bm = (blockIdx.x % NB) * 128;
    const int l15 = lane & 15;
    const float* A = (seg == 0) ? A0 : (seg == 1) ? A1 : (seg == 2) ? A2 : A3;
    const u16* B = (seg == 0) ? Bg : Bx;
    const float* bias = (seg == 0) ? bg : bx;
    u16* C = (seg == 0) ? C0 : (seg == 1) ? C1 : (seg == 2) ? C2 : C3;
    const float* asP = (seg == 0) ? as_g : (seg == 2) ? nullptr : as_x;
    const float* adP = (seg == 0) ? ad_g : (seg == 2) ? ad_x : nullptr;
    float* esP = (seg == 0) ? es1 : (seg == 1) ? esC : (seg == 3) ? esS : nullptr;
    float* edP = (seg == 0) ? ed1 : (seg == 2) ? edD : nullptr;

    f32x4 acc[4][4];
#pragma unroll
    for (int m = 0; m < 4; ++m)
#pragma unroll
        for (int n = 0; n < 4; ++n) acc[m][n] = (f32x4)0.f;

    auto STAGE = [&](int buf, int kb) {
        const int k0g = kb * 32;
        // A: 1024 16B slots (128 rows x 8 units of 4 floats)
#pragma unroll
        for (int i = 0; i < 2; ++i) {
            int s = i * 512 + tid;
            int row = s >> 3, c8 = s & 7;
            int gr = min(bm + row, M - 1);
            int gcol = k0g + ((c8 ^ (row & 7)) << 2);
            gload16(A + (size_t)gr * 256 + gcol, As_raw[buf] + s * 16);
        }
        // B: 1024 16B slots (256 rows x 4 units of 8 bf16)
#pragma unroll
        for (int i = 0; i < 2; ++i) {
            int s = i * 512 + tid;
            int row = s >> 2, c4 = s & 3;
            int gcol = k0g + (c4 ^ ((row >> 1) & 3)) * 8;
            gload16(B + (size_t)row * 256 + gcol, Bs_raw[buf] + s * 16);
        }
    };

    STAGE(0, 0);
    __syncthreads();
    for (int kb = 0; kb < 8; ++kb) {
        const int cur = kb & 1;
        if (kb < 7) STAGE(cur ^ 1, kb + 1);   // in flight during compute
        const int kc = lane >> 4;             // 0..3: which 8-k chunk
        bf16x8 af[4], bfr[4];
#pragma unroll
        for (int m = 0; m < 4; ++m) {
            int row = wr * 64 + m * 16 + l15;
            int u0 = (2 * kc) ^ (row & 7);
            f32x4 lo = *(const f32x4*)(As_raw[cur] + row * 128 + u0 * 16);
            f32x4 hi = *(const f32x4*)(As_raw[cur] + row * 128 + (u0 ^ 1) * 16);
            union { unsigned u[4]; bf16x8 v; } cv;
            cv.u[0] = pk2(lo.x, lo.y); cv.u[1] = pk2(lo.z, lo.w);
            cv.u[2] = pk2(hi.x, hi.y); cv.u[3] = pk2(hi.z, hi.w);
            af[m] = cv.v;
        }
#pragma unroll
        for (int n = 0; n < 4; ++n) {
            int row = wc * 64 + n * 16 + l15;
            bfr[n] = *(const bf16x8*)(Bs_raw[cur] + row * 64 +
                                      ((kc ^ ((row >> 1) & 3)) << 4));
        }
#pragma unroll
        for (int m = 0; m < 4; ++m)
#pragma unroll
            for (int n = 0; n < 4; ++n)
                acc[m][n] = __builtin_amdgcn_mfma_f32_16x16x32_bf16(
                    af[m], bfr[n], acc[m][n], 0, 0, 0);
        __syncthreads();
    }
    // epilogue: C write + fused es/ed (wave covers heads hb, hb+1)
    const int hb = wc * 2;
    float cS[4], cD[4];
#pragma unroll
    for (int n = 0; n < 4; ++n) {
        int hn = hb + (n >> 1);
        int ix = (n & 1) * 16 + l15;
        cS[n] = asP ? asP[hn * 32 + ix] : 0.f;
        cD[n] = adP ? adP[hn * 32 + ix] : 0.f;
    }
#pragma unroll
    for (int m = 0; m < 4; ++m) {
#pragma unroll
        for (int j = 0; j < 4; ++j) {
            int gr = bm + wr * 64 + m * 16 + (lane >> 4) * 4 + j;
            float tmp[4];
#pragma unroll
            for (int n = 0; n < 4; ++n)
                tmp[n] = acc[m][n][j] + bias[wc * 64 + n * 16 + l15];
            if (gr < M) {
#pragma unroll
                for (int n = 0; n < 4; ++n)
                    C[(size_t)gr * 256 + wc * 64 + n * 16 + l15] = f2b(tmp[n]);
            }
#pragma unroll
            for (int g = 0; g < 2; ++g) {
                if (esP) {
                    float ps = cS[2 * g] * tmp[2 * g] + cS[2 * g + 1] * tmp[2 * g + 1];
                    ps = rsum16(ps);
                    if (l15 == 0 && gr < M) esP[(size_t)gr * 8 + hb + g] = ps * LOG2E;
                }
                if (edP) {
                    float pd = cD[2 * g] * tmp[2 * g] + cD[2 * g + 1] * tmp[2 * g + 1];
                    pd = rsum16(pd);
                    if (l15 == 0 && gr < M) edP[(size_t)gr * 8 + hb + g] = pd * LOG2E;
                }
            }
        }
    }
}

// ---------- softmax gather (no max-tracking), 2-deep pipelined per segment ----
__device__ __forceinline__ void run_seg(
    const int* __restrict__ srcs, int start, int deg,
    const float* __restrict__ es, const u16* __restrict__ Wh,
    float edv, int o, int hh,
    float& psum, float4& a) {
    psum = 0.f;
    a = make_float4(0.f, 0.f, 0.f, 0.f);
    if (deg <= 0) return;
    int sP = srcs[start];
    int sN = (deg > 1) ? srcs[start + 1] : sP;
    float rawP = es[sP * 8 + hh];
    ushort4 wP = *(const ushort4*)(Wh + (size_t)sP * FEATS + o);
    for (int j = 0; j < deg; ++j) {
        int sNN = (j + 2 < deg) ? srcs[start + j + 2] : sN;
        float rawN = es[sN * 8 + hh];
        ushort4 wN = *(const ushort4*)(Wh + (size_t)sN * FEATS + o);
        float e = rawP + edv;
        e = e > 0.f ? e : ALPHA * e;
        float pe = exp2f(e);
        psum += pe;
        a.x += pe * b2f(wP.x);
        a.y += pe * b2f(wP.y);
        a.z += pe * b2f(wP.z);
        a.w += pe * b2f(wP.w);
        rawP = rawN; wP = wN; sN = sNN;
    }
}

__global__ __launch_bounds__(256) void gather_all_kernel(
    const int* __restrict__ off, const int* __restrict__ cnt,
    const int* __restrict__ srcs,
    const float* __restrict__ es1, const float* __restrict__ ed1,
    const float* __restrict__ esC, const float* __restrict__ edD,
    const float* __restrict__ esS,
    const float* __restrict__ ab_g, const float* __restrict__ ab_x,
    const u16* __restrict__ Wh1, const u16* __restrict__ WhC,
    const u16* __restrict__ WhS3,
    u16* __restrict__ xb, u16* __restrict__ hmixb, int N) {
    int gwid = (blockIdx.x * blockDim.x + threadIdx.x) >> 6;
    if (gwid >= 2 * N) return;
    int lane = threadIdx.x & 63;
    int o = lane * 4, hh = lane >> 3;
    if (gwid < N) {
        int node = gwid;
        float edv = ed1[node * 8 + hh] + ab_g[hh] * LOG2E;
        float psum; float4 a;
        run_seg(srcs, off[node], cnt[node], es1, Wh1, edv, o, hh, psum, a);
        float sc = (cnt[node] > 0) ? (1.0f / psum) : 0.f;
        ushort4 r;
        r.x = f2b(a.x * sc); r.y = f2b(a.y * sc);
        r.z = f2b(a.z * sc); r.w = f2b(a.w * sc);
        *(ushort4*)(xb + (size_t)node * FEATS + o) = r;
    } else {
        int node = gwid - N;
        float edv = edD[node * 8 + hh] + ab_x[hh] * LOG2E;
        int st2 = off[N + node],     dg2 = cnt[N + node];
        int st3 = off[2 * N + node], dg3 = cnt[2 * N + node];
        float ps2, ps3;
        float4 a2, a3;
        if (dg2 > 0 && dg3 > 0) {
            ps2 = 0.f; ps3 = 0.f;
            a2 = make_float4(0.f, 0.f, 0.f, 0.f);
            a3 = make_float4(0.f, 0.f, 0.f, 0.f);
            int sP2 = srcs[st2];
            int sN2 = (dg2 > 1) ? srcs[st2 + 1] : sP2;
            float r2 = esC[sP2 * 8 + hh];
            ushort4 w2 = *(const ushort4*)(WhC + (size_t)sP2 * FEATS + o);
            int sP3 = srcs[st3];
            int sN3 = (dg3 > 1) ? srcs[st3 + 1] : sP3;
            float r3 = esS[sP3 * 8 + hh];
            ushort4 w3 = *(const ushort4*)(WhS3 + (size_t)sP3 * FEATS + o);
            int j2 = 0, j3 = 0;
            const int c = min(dg2, dg3);
            for (int t = 0; t < c; ++t) {
                int sNN2 = (j2 + 2 < dg2) ? srcs[st2 + j2 + 2] : sN2;
                float rn2 = esC[sN2 * 8 + hh];
                ushort4 wn2 = *(const ushort4*)(WhC + (size_t)sN2 * FEATS + o);
                int sNN3 = (j3 + 2 < dg3) ? srcs[st3 + j3 + 2] : sN3;
                float rn3 = esS[sN3 * 8 + hh];
                ushort4 wn3 = *(const ushort4*)(WhS3 + (size_t)sN3 * FEATS + o);
                float e2 = r2 + edv; e2 = e2 > 0.f ? e2 : ALPHA * e2;
                float p2 = exp2f(e2);
                ps2 += p2;
                a2.x += p2 * b2f(w2.x); a2.y += p2 * b2f(w2.y);
                a2.z += p2 * b2f(w2.z); a2.w += p2 * b2f(w2.w);
                float e3 = r3 + edv; e3 = e3 > 0.f ? e3 : ALPHA * e3;
                float p3 = exp2f(e3);
                ps3 += p3;
                a3.x += p3 * b2f(w3.x); a3.y += p3 * b2f(w3.y);
                a3.z += p3 * b2f(w3.z); a3.w += p3 * b2f(w3.w);
                r2 = rn2; w2 = wn2; sN2 = sNN2; ++j2;
                r3 = rn3; w3 = wn3; sN3 = sNN3; ++j3;
            }
            for (; j2 < dg2; ++j2) {
                int sNN2 = (j2 + 2 < dg2) ? srcs[st2 + j2 + 2] : sN2;
                float rn2 = esC[sN2 * 8 + hh];
                ushort4 wn2 = *(const ushort4*)(WhC + (size_t)sN2 * FEATS + o);
                float e2 = r2 + edv; e2 = e2 > 0.f ? e2 : ALPHA * e2;
                float p2 = exp2f(e2);
                ps2 += p2;
                a2.x += p2 * b2f(w2.x); a2.y += p2 * b2f(w2.y);
                a2.z += p2 * b2f(w2.z); a2.w += p2 * b2f(w2.w);
                r2 = rn2; w2 = wn2; sN2 = sNN2;
            }
            for (; j3 < dg3; ++j3) {
                int sNN3 = (j3 + 2 < dg3) ? srcs[st3 + j3 + 2] : sN3;
                float rn3 = esS[sN3 * 8 + hh];
                ushort4 wn3 = *(const ushort4*)(WhS3 + (size_t)sN3 * FEATS + o);
                float e3 = r3 + edv; e3 = e3 > 0.f ? e3 : ALPHA * e3;
                float p3 = exp2f(e3);
                ps3 += p3;
                a3.x += p3 * b2f(w3.x); a3.y += p3 * b2f(w3.y);
                a3.z += p3 * b2f(w3.z); a3.w += p3 * b2f(w3.w);
                r3 = rn3; w3 = wn3; sN3 = sNN3;
            }
        } else {
            run_seg(srcs, st2, dg2, esC, WhC, edv, o, hh, ps2, a2);
            run_seg(srcs, st3, dg3, esS, WhS3, edv, o, hh, ps3, a3);
        }
        float sc2 = (dg2 > 0) ? (0.5f / ps2) : 0.f;
        float sc3 = (dg3 > 0) ? (0.5f / ps3) : 0.f;
        ushort4 r;
        r.x = f2b(a2.x * sc2 + a3.x * sc3);
        r.y = f2b(a2.y * sc2 + a3.y * sc3);
        r.z = f2b(a2.z * sc2 + a3.z * sc3);
        r.w = f2b(a2.w * sc2 + a3.w * sc3);
        *(ushort4*)(hmixb + (size_t)node * FEATS + o) = r;
    }
}

// ---------- fused GRU: 8 waves, 128 x 192, BK=32 double-buffered -------------
// 16 pipelined steps: t = pass*8 + kb; prefetch crosses the pass boundary.
__global__ __launch_bounds__(512, 4) void gru_fused_kernel(
    const u16* __restrict__ xb, const u16* __restrict__ hmixb,
    const u16* __restrict__ Bihr, const u16* __restrict__ Bhhr,
    const float* __restrict__ b_ih, const float* __restrict__ b_hh,
    float* __restrict__ out, int M) {
    __shared__ char As[2][8192];    // 128 rows x 32 bf16
    __shared__ char Bs[2][12288];   // 192 rows x 32 bf16
    const int tid = threadIdx.x;
    const int lane = tid & 63;
    const int wid = tid >> 6;
    const int wr = wid >> 2, wq = wid & 3;
    const int bt = blockIdx.x;
    const int bm = blockIdx.y * 128;
    const int l15 = lane & 15;

    f32x4 acc[4][3], acc2[4];
#pragma unroll
    for (int m = 0; m < 4; ++m) {
#pragma unroll
        for (int g = 0; g < 3; ++g) acc[m][g] = (f32x4)0.f;
        acc2[m] = (f32x4)0.f;
    }

    auto STAGE = [&](int buf, int t) {
        const int pass = t >> 3, kb = t & 7;
        const u16* A = pass ? hmixb : xb;
        const u16* B = pass ? Bhhr : Bihr;
        const int k0g = kb * 32;
        {   // A: 512 slots (128 rows x 4 units)
            int s = tid;
            int row = s >> 2, c4 = s & 3;
            int gr = min(bm + row, M - 1);
            int gcol = k0g + (c4 ^ ((row >> 1) & 3)) * 8;
            gload16(A + (size_t)gr * 256 + gcol, As[buf] + s * 16);
        }
#pragma unroll
        for (int i = 0; i < 2; ++i) {   // B: 768 slots (192 rows x 4 units)
            int s = i * 512 + tid;
            if (s < 768) {
                int row = s >> 2, c4 = s & 3;
                int gcol = k0g + (c4 ^ ((row >> 1) & 3)) * 8;
                gload16(B + (size_t)(bt * 192 + row) * 256 + gcol, Bs[buf] + s * 16);
            }
        }
    };

    STAGE(0, 0);
    __syncthreads();
    for (int t = 0; t < 16; ++t) {
        const int cur = t & 1;
        if (t < 15) STAGE(cur ^ 1, t + 1);
        const int pass = t >> 3;
        const int kc = lane >> 4;
        bf16x8 af[4], bfr[3];
#pragma unroll
        for (int m = 0; m < 4; ++m) {
            int row = wr * 64 + m * 16 + l15;
            af[m] = *(const bf16x8*)(As[cur] + row * 64 +
                                     ((kc ^ ((row >> 1) & 3)) << 4));
        }
#pragma unroll
        for (int g = 0; g < 3; ++g) {
            int row = wq * 48 + g * 16 + l15;
            bfr[g] = *(const bf16x8*)(Bs[cur] + row * 64 +
                                      ((kc ^ ((row >> 1) & 3)) << 4));
        }
#pragma unroll
        for (int m = 0; m < 4; ++m) {
#pragma unroll
            for (int g = 0; g < 3; ++g) {
                if (pass == 1 && g == 2)
                    acc2[m] = __builtin_amdgcn_mfma_f32_16x16x32_bf16(
                        af[m], bfr[g], acc2[m], 0, 0, 0);
                else
                    acc[m][g] = __builtin_amdgcn_mfma_f32_16x16x32_bf16(
                        af[m], bfr[g], acc[m][g], 0, 0, 0);
            }
        }
        __syncthreads();
    }
    const int j = (bt * 4 + wq) * 16 + l15;
    const float bir = b_ih[j], biz = b_ih[256 + j], bin = b_ih[512 + j];
    const float bhr = b_hh[j], bhz = b_hh[256 + j], bhn = b_hh[512 + j];
#pragma unroll
    for (int m = 0; m < 4; ++m) {
#pragma unroll
        for (int jj = 0; jj < 4; ++jj) {
            int row = bm + wr * 64 + m * 16 + (lane >> 4) * 4 + jj;
            if (row < M) {
                float gr_ = acc[m][0][jj] + bir + bhr;
                float gz_ = acc[m][1][jj] + biz + bhz;
                float rr = 1.f / (1.f + exp2f(-gr_ * LOG2E));
                float zz = 1.f / (1.f + exp2f(-gz_ * LOG2E));
                float nn = tanhf(acc[m][2][jj] + bin + rr * (acc2[m][jj] + bhn));
                float hm = b2f(hmixb[(size_t)row * 256 + j]);
                out[(size_t)row * 256 + j] = (1.f - zz) * nn + zz * hm;
            }
        }
    }
}

// ---------- launch ----------
extern "C" void kernel_launch(void* const* d_in, const int* in_sizes, int n_in,
                              void* d_out, int out_size, void* d_ws, size_t ws_size,
                              hipStream_t stream) {
    const float* h        = (const float*)d_in[0];
    const float* hp_cnt   = (const float*)d_in[1];
    const float* hp_sup   = (const float*)d_in[2];
    const float* hp_dst   = (const float*)d_in[3];
    const float* W_gat    = (const float*)d_in[4];
    const float* b_gat    = (const float*)d_in[5];
    const float* as_gat   = (const float*)d_in[6];
    const float* ad_gat   = (const float*)d_in[7];
    const float* ab_gat   = (const float*)d_in[8];
    const float* W_x      = (const float*)d_in[9];
    const float* b_x      = (const float*)d_in[10];
    const float* as_x     = (const float*)d_in[11];
    const float* ad_x     = (const float*)d_in[12];
    const float* ab_x     = (const float*)d_in[13];
    const float* W_ih     = (const float*)d_in[14];
    const float* W_hh     = (const float*)d_in[15];
    const float* b_ih     = (const float*)d_in[16];
    const float* b_hh     = (const float*)d_in[17];
    const int* e_src      = (const int*)d_in[18];
    const int* e_dst      = (const int*)d_in[19];
    const int* ec_src     = (const int*)d_in[20];
    const int* ec_dst     = (const int*)d_in[21];
    const int* es_src     = (const int*)d_in[22];
    const int* es_dst     = (const int*)d_in[23];

    const int N = in_sizes[0] / FEATS;
    const int E = in_sizes[18];
    const int N8 = N * HEADS;
    const int N3 = 3 * N;
    const int NBLK3 = (N3 + 1023) / 1024;
    const int NB128 = (N + 127) / 128;

    char* ws = (char*)d_ws;
    size_t p = 0;
    u16* Wh1   = (u16*)(ws + p); p += (size_t)N * FEATS * 2;
    u16* WhC   = (u16*)(ws + p); p += (size_t)N * FEATS * 2;
    u16* WhD   = (u16*)(ws + p); p += (size_t)N * FEATS * 2;
    u16* WhS3  = (u16*)(ws + p); p += (size_t)N * FEATS * 2;
    u16* xb    = (u16*)(ws + p); p += (size_t)N * FEATS * 2;
    u16* hmixb = (u16*)(ws + p); p += (size_t)N * FEATS * 2;
    float* es1 = (float*)(ws + p); p += (size_t)N8 * 4;
    float* ed1 = (float*)(ws + p); p += (size_t)N8 * 4;
    float* esC = (float*)(ws + p); p += (size_t)N8 * 4;
    float* edD = (float*)(ws + p); p += (size_t)N8 * 4;
    float* esS = (float*)(ws + p); p += (size_t)N8 * 4;
    int* cnt3  = (int*)(ws + p); p += (size_t)N3 * 4;
    int* off3  = (int*)(ws + p); p += (size_t)N3 * 4;
    int* cur3  = (int*)(ws + p); p += (size_t)N3 * 4;
    int* blks  = (int*)(ws + p); p += 1024;
    int* srcs3 = (int*)(ws + p); p += (size_t)3 * E * 4;
    u16* Bgat  = (u16*)(ws + p); p += 65536 * 2;
    u16* Bx    = (u16*)(ws + p); p += 65536 * 2;
    u16* Bihr  = (u16*)(ws + p); p += 196608 * 2;
    u16* Bhhr  = (u16*)(ws + p); p += 196608 * 2;

    const dim3 blk(256);
    const dim3 blk512(512);
    const int g3E256 = (3 * E + 255) / 256;

    // prep || count (both LDS-free), after cnt3 zeroing
    hipMemsetAsync(cnt3, 0, (size_t)N3 * 4, stream);
    prep_count_kernel<<<2048 + g3E256, blk, 0, stream>>>(
        W_gat, W_x, W_ih, W_hh, Bgat, Bx, Bihr, Bhhr,
        e_dst, ec_dst, es_dst, cnt3, E, N);

    // scan
    scan1_kernel<<<NBLK3, blk, 0, stream>>>(cnt3, off3, blks, N3);
    scan2_kernel<<<1, blk, 0, stream>>>(blks, NBLK3);
    scan3_kernel<<<(N3 + 255) / 256, blk, 0, stream>>>(off3, cur3, blks, N3);

    // fill3: dedicated high-occupancy kernel
    fill3_kernel<<<g3E256, blk, 0, stream>>>(e_src, e_dst, ec_src, ec_dst,
                                             es_src, es_dst, cur3, srcs3, E, N);

    // 4 projections + fused es/ed (BK=32 double-buffered)
    proj4_kernel<<<4 * NB128, blk512, 0, stream>>>(
        h, hp_cnt, hp_dst, hp_sup, Bgat, Bx, b_gat, b_x,
        Wh1, WhC, WhD, WhS3,
        as_gat, ad_gat, as_x, ad_x,
        es1, ed1, esC, edD, esS, N, NB128);

    // all three GATs in one launch (2N waves; dual-segment waves interleaved)
    gather_all_kernel<<<(2 * N * 64 + 255) / 256, blk, 0, stream>>>(
        off3, cnt3, srcs3, es1, ed1, esC, edD, esS, ab_gat, ab_x,
        Wh1, WhC, WhS3, xb, hmixb, N);

    // fused GRU (BK=32 double-buffered)
    gru_fused_kernel<<<dim3(4, NB128), blk512, 0, stream>>>(
        xb, hmixb, Bihr, Bhhr, b_ih, b_hh, (float*)d_out, N);
}

// Round 12
// 472.740 us; speedup vs baseline: 1.0295x; 1.0295x over previous
//
#include <hip/hip_runtime.h>
#include <math.h>

#define ALPHA 0.2f
#define LOG2E 1.44269504088896f

constexpr int FEATS = 256;
constexpr int HEADS = 8;

typedef unsigned short u16;
typedef __attribute__((ext_vector_type(8))) short bf16x8;
typedef __attribute__((ext_vector_type(4))) float f32x4;

__device__ __forceinline__ u16 f2b(float f) {            // RNE
    unsigned u = __float_as_uint(f);
    u += 0x7FFF + ((u >> 16) & 1);
    return (u16)(u >> 16);
}
__device__ __forceinline__ float b2f(u16 x) {
    return __uint_as_float(((unsigned)x) << 16);
}
__device__ __forceinline__ unsigned pk2(float lo, float hi) {
    return __builtin_amdgcn_perm(__float_as_uint(hi), __float_as_uint(lo), 0x07060302u);
}
__device__ __forceinline__ void gload16(const void* g, void* l) {
    __builtin_amdgcn_global_load_lds(
        (const __attribute__((address_space(1))) unsigned int*)g,
        (__attribute__((address_space(3))) unsigned int*)l, 16, 0, 0);
}
__device__ __forceinline__ float rsum16(float v) {
    v += __shfl_xor(v, 1); v += __shfl_xor(v, 2);
    v += __shfl_xor(v, 4); v += __shfl_xor(v, 8);
    return v;
}

// ---------- prep (weight convert/reorder) || count3 (CSR histogram) ----------
__global__ void prep_count_kernel(
    const float* __restrict__ W_gat, const float* __restrict__ W_x,
    const float* __restrict__ W_ih, const float* __restrict__ W_hh,
    u16* __restrict__ Bgat, u16* __restrict__ Bx,
    u16* __restrict__ Bihr, u16* __restrict__ Bhhr,
    const int* __restrict__ d0, const int* __restrict__ d1,
    const int* __restrict__ d2, int* __restrict__ cnt, int E, int N) {
    int b = blockIdx.x;
    if (b < 2048) {
        int i = b * 256 + threadIdx.x;   // [0, 524288)
        if (i < 131072) {
            int j = i & 65535;
            int n = j >> 8, f = j & 255;
            int h2 = n >> 5, d = n & 31;
            const float* W = (i < 65536) ? W_gat : W_x;
            u16* Bt = (i < 65536) ? Bgat : Bx;
            Bt[j] = f2b(W[(h2 * 256 + f) * 32 + d]);
        } else {
            int x = i - 131072;
            int lin = (x < 196608) ? x : x - 196608;
            int c = lin >> 8, k = lin & 255;
            int q = c / 48, rr = c - q * 48;
            int g = rr >> 4, jl = rr & 15;
            int orig = (g * 256 + q * 16 + jl) * 256 + k;
            if (x < 196608) Bihr[lin] = f2b(W_ih[orig]);
            else            Bhhr[lin] = f2b(W_hh[orig]);
        }
    } else {
        int i = (b - 2048) * 256 + threadIdx.x;
        if (i >= 3 * E) return;
        if (i < E) atomicAdd(&cnt[d0[i]], 1);
        else if (i < 2 * E) atomicAdd(&cnt[N + d1[i - E]], 1);
        else atomicAdd(&cnt[2 * N + d2[i - 2 * E]], 1);
    }
}

// ---------- scan (1024 elems/block, 2-level) ----------
__global__ void scan1_kernel(const int* __restrict__ cnt, int* __restrict__ off,
                             int* __restrict__ blksum, int n) {
    __shared__ int tmp[256];
    int t = threadIdx.x;
    int base = blockIdx.x * 1024 + t * 4;
    int v[4];
#pragma unroll
    for (int k = 0; k < 4; ++k) v[k] = (base + k < n) ? cnt[base + k] : 0;
    int s = v[0] + v[1] + v[2] + v[3];
    tmp[t] = s;
    __syncthreads();
    for (int st = 1; st < 256; st <<= 1) {
        int add = (t >= st) ? tmp[t - st] : 0;
        __syncthreads();
        tmp[t] += add;
        __syncthreads();
    }
    int ex = tmp[t] - s;
#pragma unroll
    for (int k = 0; k < 4; ++k) {
        if (base + k < n) off[base + k] = ex;
        ex += v[k];
    }
    if (t == 255) blksum[blockIdx.x] = tmp[255];
}
__global__ void scan2_kernel(int* __restrict__ blksum, int nb) {
    __shared__ int tmp[256];
    int t = threadIdx.x;
    int v = (t < nb) ? blksum[t] : 0;
    tmp[t] = v;
    __syncthreads();
    for (int s = 1; s < 256; s <<= 1) {
        int add = (t >= s) ? tmp[t - s] : 0;
        __syncthreads();
        tmp[t] += add;
        __syncthreads();
    }
    if (t < nb) blksum[t] = tmp[t] - v;
}
__global__ void scan3_kernel(int* __restrict__ off, int* __restrict__ cur,
                             const int* __restrict__ blksum, int n) {
    int i = blockIdx.x * blockDim.x + threadIdx.x;
    if (i < n) {
        int v = off[i] + blksum[i >> 10];
        off[i] = v;
        cur[i] = v;
    }
}

// ---------- fill3: dedicated kernel (0 LDS -> max occupancy) ----------
__global__ void fill3_kernel(const int* __restrict__ s0, const int* __restrict__ d0,
                             const int* __restrict__ s1, const int* __restrict__ d1,
                             const int* __restrict__ s2, const int* __restrict__ d2,
                             int* __restrict__ cur, int* __restrict__ srcs, int E, int N) {
    int i = blockIdx.x * blockDim.x + threadIdx.x;
    if (i >= 3 * E) return;
    int s, slot;
    if (i < E) { s = s0[i]; slot = d0[i]; }
    else if (i < 2 * E) { s = s1[i - E]; slot = N + d1[i - E]; }
    else { s = s2[i - 2 * E]; slot = 2 * N + d2[i - 2 * E]; }
    int p = atomicAdd(&cur[slot], 1);
    srcs[p] = s;
}

// ---------- merged 4-way projection GEMM + fused es/ed epilogue (r10 form) ----
__global__ __launch_bounds__(512, 4) void proj4_kernel(
    const float* __restrict__ A0, const float* __restrict__ A1,
    const float* __restrict__ A2, const float* __restrict__ A3,
    const u16* __restrict__ Bg, const u16* __restrict__ Bx,
    const float* __restrict__ bg, const float* __restrict__ bx,
    u16* __restrict__ C0, u16* __restrict__ C1,
    u16* __restrict__ C2, u16* __restrict__ C3,
    const float* __restrict__ as_g, const float* __restrict__ ad_g,
    const float* __restrict__ as_x, const float* __restrict__ ad_x,
    float* __restrict__ es1, float* __restrict__ ed1,
    float* __restrict__ esC, float* __restrict__ edD,
    float* __restrict__ esS,
    int M, int NB) {
    __shared__ char As_raw[32768];  // 128 x 64 f32, 16B-unit swizzled
    __shared__ char Bs_raw[32768];  // 256 x 64 bf16, swizzled
    const int tid = threadIdx.x;
    const int lane = tid & 63;
    const int wid = tid >> 6;                 // 8 waves
    const int wr = wid >> 2, wc = wid & 3;    // 2 x 4
    const int seg = blockIdx.x / NB;
    const int bm = (blockIdx.x % NB) * 128;
    const int l15 = lane & 15;
    const float* A = (seg == 0) ? A0 : (seg == 1) ? A1 : (seg == 2) ? A2 : A3;
    const u16* B = (seg == 0) ? Bg : Bx;
    const float* bias = (seg == 0) ? bg : bx;
    u16* C = (seg == 0) ? C0 : (seg == 1) ? C1 : (seg == 2) ? C2 : C3;
    const float* asP = (seg == 0) ? as_g : (seg == 2) ? nullptr : as_x;
    const float* adP = (seg == 0) ? ad_g : (seg == 2) ? ad_x : nullptr;
    float* esP = (seg == 0) ? es1 : (seg == 1) ? esC : (seg == 3) ? esS : nullptr;
    float* edP = (seg == 0) ? ed1 : (seg == 2) ? edD : nullptr;

    f32x4 acc[4][4];
#pragma unroll
    for (int m = 0; m < 4; ++m)
#pragma unroll
        for (int n = 0; n < 4; ++n) acc[m][n] = (f32x4)0.f;

    for (int kb = 0; kb < 4; ++kb) {
        const int k0g = kb * 64;
#pragma unroll
        for (int i = 0; i < 4; ++i) {
            int s = i * 512 + tid;            // A: 2048 16B slots
            int row = s >> 4, c16 = s & 15;
            int gr = min(bm + row, M - 1);
            int gcol = k0g + ((c16 ^ (row & 7)) << 2);
            gload16(A + (size_t)gr * 256 + gcol, As_raw + s * 16);
        }
#pragma unroll
        for (int i = 0; i < 4; ++i) {
            int s = i * 512 + tid;            // B: 2048 16B slots
            int row = s >> 3, c16 = s & 7;
            int gcol = k0g + (c16 ^ (row & 7)) * 8;
            gload16(B + (size_t)row * 256 + gcol, Bs_raw + s * 16);
        }
        __syncthreads();
#pragma unroll
        for (int kk = 0; kk < 2; ++kk) {
            const int kc = (kk * 32 + (lane >> 4) * 8) >> 3;
            bf16x8 af[4], bfr[4];
#pragma unroll
            for (int m = 0; m < 4; ++m) {
                int row = wr * 64 + m * 16 + l15;
                int r7 = row & 7;
                int u0 = (2 * kc) ^ r7;
                f32x4 lo = *(const f32x4*)(As_raw + row * 256 + u0 * 16);
                f32x4 hi = *(const f32x4*)(As_raw + row * 256 + (u0 ^ 1) * 16);
                union { unsigned u[4]; bf16x8 v; } cv;
                cv.u[0] = pk2(lo.x, lo.y); cv.u[1] = pk2(lo.z, lo.w);
                cv.u[2] = pk2(hi.x, hi.y); cv.u[3] = pk2(hi.z, hi.w);
                af[m] = cv.v;
            }
#pragma unroll
            for (int n = 0; n < 4; ++n) {
                int row = wc * 64 + n * 16 + l15;
                bfr[n] = *(const bf16x8*)(Bs_raw + row * 128 + ((kc ^ (row & 7)) << 4));
            }
#pragma unroll
            for (int m = 0; m < 4; ++m)
#pragma unroll
                for (int n = 0; n < 4; ++n)
                    acc[m][n] = __builtin_amdgcn_mfma_f32_16x16x32_bf16(
                        af[m], bfr[n], acc[m][n], 0, 0, 0);
        }
        __syncthreads();
    }
    const int hb = wc * 2;
    float cS[4], cD[4];
#pragma unroll
    for (int n = 0; n < 4; ++n) {
        int hn = hb + (n >> 1);
        int ix = (n & 1) * 16 + l15;
        cS[n] = asP ? asP[hn * 32 + ix] : 0.f;
        cD[n] = adP ? adP[hn * 32 + ix] : 0.f;
    }
#pragma unroll
    for (int m = 0; m < 4; ++m) {
#pragma unroll
        for (int j = 0; j < 4; ++j) {
            int gr = bm + wr * 64 + m * 16 + (lane >> 4) * 4 + j;
            float tmp[4];
#pragma unroll
            for (int n = 0; n < 4; ++n)
                tmp[n] = acc[m][n][j] + bias[wc * 64 + n * 16 + l15];
            if (gr < M) {
#pragma unroll
                for (int n = 0; n < 4; ++n)
                    C[(size_t)gr * 256 + wc * 64 + n * 16 + l15] = f2b(tmp[n]);
            }
#pragma unroll
            for (int g = 0; g < 2; ++g) {
                if (esP) {
                    float ps = cS[2 * g] * tmp[2 * g] + cS[2 * g + 1] * tmp[2 * g + 1];
                    ps = rsum16(ps);
                    if (l15 == 0 && gr < M) esP[(size_t)gr * 8 + hb + g] = ps * LOG2E;
                }
                if (edP) {
                    float pd = cD[2 * g] * tmp[2 * g] + cD[2 * g + 1] * tmp[2 * g + 1];
                    pd = rsum16(pd);
                    if (l15 == 0 && gr < M) edP[(size_t)gr * 8 + hb + g] = pd * LOG2E;
                }
            }
        }
    }
}

// ---------- gather helpers ----------
__device__ __forceinline__ ushort4 ldwh(const u16* __restrict__ Wh, int s, int o) {
    return *(const ushort4*)(Wh + (size_t)s * FEATS + o);
}
__device__ __forceinline__ void edge_acc(float raw, ushort4 w, float edv,
                                         float& ps, float4& a) {
    float e = raw + edv;
    e = fmaxf(e, ALPHA * e);       // leaky relu for 0<ALPHA<1
    float pe = exp2f(e);           // inputs pre-scaled by log2(e)
    ps += pe;
    a.x += pe * b2f(w.x); a.y += pe * b2f(w.y);
    a.z += pe * b2f(w.z); a.w += pe * b2f(w.w);
}

// single 2-deep chain
__device__ __forceinline__ void run_seg(
    const int* __restrict__ srcs, int start, int deg,
    const float* __restrict__ es, const u16* __restrict__ Wh,
    float edv, int o, int hh,
    float& psum, float4& a) {
    psum = 0.f;
    a = make_float4(0.f, 0.f, 0.f, 0.f);
    if (deg <= 0) return;
    int sN = (deg > 1) ? srcs[start + 1] : srcs[start];
    float rawP = es[srcs[start] * 8 + hh];
    ushort4 wP = ldwh(Wh, srcs[start], o);
    for (int j = 0; j < deg; ++j) {
        int sNN = (j + 2 < deg) ? srcs[start + j + 2] : sN;
        float rawN = es[sN * 8 + hh];
        ushort4 wN = ldwh(Wh, sN, o);
        edge_acc(rawP, wP, edv, psum, a);
        rawP = rawN; wP = wN; sN = sNN;
    }
}

// two interleaved 2-deep chains over the two halves of one segment (exact)
__device__ __forceinline__ void run_seg2(
    const int* __restrict__ srcs, int start, int deg,
    const float* __restrict__ es, const u16* __restrict__ Wh,
    float edv, int o, int hh,
    float& psum, float4& a) {
    if (deg < 4) { run_seg(srcs, start, deg, es, Wh, edv, o, hh, psum, a); return; }
    const int dh = deg >> 1;           // chain A: [start, start+dh)
    const int dB = deg - dh;           // chain B: [start+dh, start+deg), dB >= dh >= 2
    float psA = 0.f, psB = 0.f;
    float4 aA = make_float4(0.f, 0.f, 0.f, 0.f);
    float4 aB = make_float4(0.f, 0.f, 0.f, 0.f);
    int sA1 = srcs[start + 1];
    int sB1 = srcs[start + dh + 1];
    float rA = es[srcs[start] * 8 + hh];
    ushort4 wA = ldwh(Wh, srcs[start], o);
    float rB = es[srcs[start + dh] * 8 + hh];
    ushort4 wB = ldwh(Wh, srcs[start + dh], o);
    for (int j = 0; j < dh; ++j) {
        int sA2 = (j + 2 < dh) ? srcs[start + j + 2] : sA1;
        float rA1 = es[sA1 * 8 + hh];
        ushort4 wA1 = ldwh(Wh, sA1, o);
        int sB2 = (j + 2 < dB) ? srcs[start + dh + j + 2] : sB1;
        float rB1 = es[sB1 * 8 + hh];
        ushort4 wB1 = ldwh(Wh, sB1, o);
        edge_acc(rA, wA, edv, psA, aA);
        edge_acc(rB, wB, edv, psB, aB);
        rA = rA1; wA = wA1; sA1 = sA2;
        rB = rB1; wB = wB1; sB1 = sB2;
    }
    for (int j = dh; j < dB; ++j)      // at most 1 iteration
        edge_acc(rB, wB, edv, psB, aB);
    psum = psA + psB;
    a = make_float4(aA.x + aB.x, aA.y + aB.y, aA.z + aB.z, aA.w + aB.w);
}

__global__ __launch_bounds__(256) void gather_all_kernel(
    const int* __restrict__ off, const int* __restrict__ cnt,
    const int* __restrict__ srcs,
    const float* __restrict__ es1, const float* __restrict__ ed1,
    const float* __restrict__ esC, const float* __restrict__ edD,
    const float* __restrict__ esS,
    const float* __restrict__ ab_g, const float* __restrict__ ab_x,
    const u16* __restrict__ Wh1, const u16* __restrict__ WhC,
    const u16* __restrict__ WhS3,
    u16* __restrict__ xb, u16* __restrict__ hmixb, int N) {
    int gwid = (blockIdx.x * blockDim.x + threadIdx.x) >> 6;
    if (gwid >= 2 * N) return;
    int lane = threadIdx.x & 63;
    int o = lane * 4, hh = lane >> 3;
    if (gwid < N) {
        int node = gwid;
        float edv = ed1[node * 8 + hh] + ab_g[hh] * LOG2E;
        float psum; float4 a;
        run_seg2(srcs, off[node], cnt[node], es1, Wh1, edv, o, hh, psum, a);
        float sc = (cnt[node] > 0) ? (1.0f / psum) : 0.f;
        ushort4 r;
        r.x = f2b(a.x * sc); r.y = f2b(a.y * sc);
        r.z = f2b(a.z * sc); r.w = f2b(a.w * sc);
        *(ushort4*)(xb + (size_t)node * FEATS + o) = r;
    } else {
        int node = gwid - N;
        float edv = edD[node * 8 + hh] + ab_x[hh] * LOG2E;
        int st2 = off[N + node],     dg2 = cnt[N + node];
        int st3 = off[2 * N + node], dg3 = cnt[2 * N + node];
        float ps2, ps3;
        float4 a2, a3;
        if (dg2 > 0 && dg3 > 0) {
            // interleaved dual-segment walk: 2 independent load chains in flight
            ps2 = 0.f; ps3 = 0.f;
            a2 = make_float4(0.f, 0.f, 0.f, 0.f);
            a3 = make_float4(0.f, 0.f, 0.f, 0.f);
            int sN2 = (dg2 > 1) ? srcs[st2 + 1] : srcs[st2];
            float r2 = esC[srcs[st2] * 8 + hh];
            ushort4 w2 = ldwh(WhC, srcs[st2], o);
            int sN3 = (dg3 > 1) ? srcs[st3 + 1] : srcs[st3];
            float r3 = esS[srcs[st3] * 8 + hh];
            ushort4 w3 = ldwh(WhS3, srcs[st3], o);
            int j2 = 0, j3 = 0;
            const int c = min(dg2, dg3);
            for (int t = 0; t < c; ++t) {
                int sNN2 = (j2 + 2 < dg2) ? srcs[st2 + j2 + 2] : sN2;
                float rn2 = esC[sN2 * 8 + hh];
                ushort4 wn2 = ldwh(WhC, sN2, o);
                int sNN3 = (j3 + 2 < dg3) ? srcs[st3 + j3 + 2] : sN3;
                float rn3 = esS[sN3 * 8 + hh];
                ushort4 wn3 = ldwh(WhS3, sN3, o);
                edge_acc(r2, w2, edv, ps2, a2);
                edge_acc(r3, w3, edv, ps3, a3);
                r2 = rn2; w2 = wn2; sN2 = sNN2; ++j2;
                r3 = rn3; w3 = wn3; sN3 = sNN3; ++j3;
            }
            for (; j2 < dg2; ++j2) {
                int sNN2 = (j2 + 2 < dg2) ? srcs[st2 + j2 + 2] : sN2;
                float rn2 = esC[sN2 * 8 + hh];
                ushort4 wn2 = ldwh(WhC, sN2, o);
                edge_acc(r2, w2, edv, ps2, a2);
                r2 = rn2; w2 = wn2; sN2 = sNN2;
            }
            for (; j3 < dg3; ++j3) {
                int sNN3 = (j3 + 2 < dg3) ? srcs[st3 + j3 + 2] : sN3;
                float rn3 = esS[sN3 * 8 + hh];
                ushort4 wn3 = ldwh(WhS3, sN3, o);
                edge_acc(r3, w3, edv, ps3, a3);
                r3 = rn3; w3 = wn3; sN3 = sNN3;
            }
        } else {
            run_seg2(srcs, st2, dg2, esC, WhC, edv, o, hh, ps2, a2);
            run_seg2(srcs, st3, dg3, esS, WhS3, edv, o, hh, ps3, a3);
        }
        float sc2 = (dg2 > 0) ? (0.5f / ps2) : 0.f;
        float sc3 = (dg3 > 0) ? (0.5f / ps3) : 0.f;
        ushort4 r;
        r.x = f2b(a2.x * sc2 + a3.x * sc3);
        r.y = f2b(a2.y * sc2 + a3.y * sc3);
        r.z = f2b(a2.z * sc2 + a3.z * sc3);
        r.w = f2b(a2.w * sc2 + a3.w * sc3);
        *(ushort4*)(hmixb + (size_t)node * FEATS + o) = r;
    }
}

// ---------- fully-fused GRU: 8 waves, 128 rows x 192 reordered cols (r10) ----
__global__ __launch_bounds__(512, 4) void gru_fused_kernel(
    const u16* __restrict__ xb, const u16* __restrict__ hmixb,
    const u16* __restrict__ Bihr, const u16* __restrict__ Bhhr,
    const float* __restrict__ b_ih, const float* __restrict__ b_hh,
    float* __restrict__ out, int M) {
    __shared__ char As[16384];   // 128 x 64 bf16
    __shared__ char Bs[24576];   // 192 x 64 bf16
    const int tid = threadIdx.x;
    const int lane = tid & 63;
    const int wid = tid >> 6;
    const int wr = wid >> 2, wq = wid & 3;
    const int bt = blockIdx.x;
    const int bm = blockIdx.y * 128;
    const int l15 = lane & 15;

    f32x4 acc[4][3], acc2[4];
#pragma unroll
    for (int m = 0; m < 4; ++m) {
#pragma unroll
        for (int g = 0; g < 3; ++g) acc[m][g] = (f32x4)0.f;
        acc2[m] = (f32x4)0.f;
    }

#pragma unroll
    for (int pass = 0; pass < 2; ++pass) {
        const u16* A = pass ? hmixb : xb;
        const u16* B = pass ? Bhhr : Bihr;
        for (int kb = 0; kb < 4; ++kb) {
            const int k0g = kb * 64;
#pragma unroll
            for (int i = 0; i < 2; ++i) {
                int s = i * 512 + tid;
                int row = s >> 3, c16 = s & 7;
                int gr = min(bm + row, M - 1);
                int gcol = k0g + (c16 ^ (row & 7)) * 8;
                gload16(A + (size_t)gr * 256 + gcol, As + s * 16);
            }
#pragma unroll
            for (int i = 0; i < 3; ++i) {
                int s = i * 512 + tid;
                int row = s >> 3, c16 = s & 7;
                int gcol = k0g + (c16 ^ (row & 7)) * 8;
                gload16(B + (size_t)(bt * 192 + row) * 256 + gcol, Bs + s * 16);
            }
            __syncthreads();
#pragma unroll
            for (int kk = 0; kk < 2; ++kk) {
                const int kc = (kk * 32 + (lane >> 4) * 8) >> 3;
                bf16x8 af[4], bfr[3];
#pragma unroll
                for (int m = 0; m < 4; ++m) {
                    int row = wr * 64 + m * 16 + l15;
                    af[m] = *(const bf16x8*)(As + row * 128 + ((kc ^ (row & 7)) << 4));
                }
#pragma unroll
                for (int g = 0; g < 3; ++g) {
                    int row = wq * 48 + g * 16 + l15;
                    bfr[g] = *(const bf16x8*)(Bs + row * 128 + ((kc ^ (row & 7)) << 4));
                }
#pragma unroll
                for (int m = 0; m < 4; ++m) {
#pragma unroll
                    for (int g = 0; g < 3; ++g) {
                        if (pass == 1 && g == 2)
                            acc2[m] = __builtin_amdgcn_mfma_f32_16x16x32_bf16(
                                af[m], bfr[g], acc2[m], 0, 0, 0);
                        else
                            acc[m][g] = __builtin_amdgcn_mfma_f32_16x16x32_bf16(
                                af[m], bfr[g], acc[m][g], 0, 0, 0);
                    }
                }
            }
            __syncthreads();
        }
    }
    const int j = (bt * 4 + wq) * 16 + l15;
    const float bir = b_ih[j], biz = b_ih[256 + j], bin = b_ih[512 + j];
    const float bhr = b_hh[j], bhz = b_hh[256 + j], bhn = b_hh[512 + j];
#pragma unroll
    for (int m = 0; m < 4; ++m) {
#pragma unroll
        for (int jj = 0; jj < 4; ++jj) {
            int row = bm + wr * 64 + m * 16 + (lane >> 4) * 4 + jj;
            if (row < M) {
                float gr_ = acc[m][0][jj] + bir + bhr;
                float gz_ = acc[m][1][jj] + biz + bhz;
                float rr = 1.f / (1.f + exp2f(-gr_ * LOG2E));
                float zz = 1.f / (1.f + exp2f(-gz_ * LOG2E));
                float nn = tanhf(acc[m][2][jj] + bin + rr * (acc2[m][jj] + bhn));
                float hm = b2f(hmixb[(size_t)row * 256 + j]);
                out[(size_t)row * 256 + j] = (1.f - zz) * nn + zz * hm;
            }
        }
    }
}

// ---------- launch ----------
extern "C" void kernel_launch(void* const* d_in, const int* in_sizes, int n_in,
                              void* d_out, int out_size, void* d_ws, size_t ws_size,
                              hipStream_t stream) {
    const float* h        = (const float*)d_in[0];
    const float* hp_cnt   = (const float*)d_in[1];
    const float* hp_sup   = (const float*)d_in[2];
    const float* hp_dst   = (const float*)d_in[3];
    const float* W_gat    = (const float*)d_in[4];
    const float* b_gat    = (const float*)d_in[5];
    const float* as_gat   = (const float*)d_in[6];
    const float* ad_gat   = (const float*)d_in[7];
    const float* ab_gat   = (const float*)d_in[8];
    const float* W_x      = (const float*)d_in[9];
    const float* b_x      = (const float*)d_in[10];
    const float* as_x     = (const float*)d_in[11];
    const float* ad_x     = (const float*)d_in[12];
    const float* ab_x     = (const float*)d_in[13];
    const float* W_ih     = (const float*)d_in[14];
    const float* W_hh     = (const float*)d_in[15];
    const float* b_ih     = (const float*)d_in[16];
    const float* b_hh     = (const float*)d_in[17];
    const int* e_src      = (const int*)d_in[18];
    const int* e_dst      = (const int*)d_in[19];
    const int* ec_src     = (const int*)d_in[20];
    const int* ec_dst     = (const int*)d_in[21];
    const int* es_src     = (const int*)d_in[22];
    const int* es_dst     = (const int*)d_in[23];

    const int N = in_sizes[0] / FEATS;
    const int E = in_sizes[18];
    const int N8 = N * HEADS;
    const int N3 = 3 * N;
    const int NBLK3 = (N3 + 1023) / 1024;
    const int NB128 = (N + 127) / 128;

    char* ws = (char*)d_ws;
    size_t p = 0;
    u16* Wh1   = (u16*)(ws + p); p += (size_t)N * FEATS * 2;
    u16* WhC   = (u16*)(ws + p); p += (size_t)N * FEATS * 2;
    u16* WhD   = (u16*)(ws + p); p += (size_t)N * FEATS * 2;
    u16* WhS3  = (u16*)(ws + p); p += (size_t)N * FEATS * 2;
    u16* xb    = (u16*)(ws + p); p += (size_t)N * FEATS * 2;
    u16* hmixb = (u16*)(ws + p); p += (size_t)N * FEATS * 2;
    float* es1 = (float*)(ws + p); p += (size_t)N8 * 4;
    float* ed1 = (float*)(ws + p); p += (size_t)N8 * 4;
    float* esC = (float*)(ws + p); p += (size_t)N8 * 4;
    float* edD = (float*)(ws + p); p += (size_t)N8 * 4;
    float* esS = (float*)(ws + p); p += (size_t)N8 * 4;
    int* cnt3  = (int*)(ws + p); p += (size_t)N3 * 4;
    int* off3  = (int*)(ws + p); p += (size_t)N3 * 4;
    int* cur3  = (int*)(ws + p); p += (size_t)N3 * 4;
    int* blks  = (int*)(ws + p); p += 1024;
    int* srcs3 = (int*)(ws + p); p += (size_t)3 * E * 4;
    u16* Bgat  = (u16*)(ws + p); p += 65536 * 2;
    u16* Bx    = (u16*)(ws + p); p += 65536 * 2;
    u16* Bihr  = (u16*)(ws + p); p += 196608 * 2;
    u16* Bhhr  = (u16*)(ws + p); p += 196608 * 2;

    const dim3 blk(256);
    const dim3 blk512(512);
    const int g3E256 = (3 * E + 255) / 256;

    // prep || count (both LDS-free), after cnt3 zeroing
    hipMemsetAsync(cnt3, 0, (size_t)N3 * 4, stream);
    prep_count_kernel<<<2048 + g3E256, blk, 0, stream>>>(
        W_gat, W_x, W_ih, W_hh, Bgat, Bx, Bihr, Bhhr,
        e_dst, ec_dst, es_dst, cnt3, E, N);

    // scan
    scan1_kernel<<<NBLK3, blk, 0, stream>>>(cnt3, off3, blks, N3);
    scan2_kernel<<<1, blk, 0, stream>>>(blks, NBLK3);
    scan3_kernel<<<(N3 + 255) / 256, blk, 0, stream>>>(off3, cur3, blks, N3);

    // fill3: dedicated high-occupancy kernel
    fill3_kernel<<<g3E256, blk, 0, stream>>>(e_src, e_dst, ec_src, ec_dst,
                                             es_src, es_dst, cur3, srcs3, E, N);

    // 4 projections + fused es/ed (full 256-col tiles)
    proj4_kernel<<<4 * NB128, blk512, 0, stream>>>(
        h, hp_cnt, hp_dst, hp_sup, Bgat, Bx, b_gat, b_x,
        Wh1, WhC, WhD, WhS3,
        as_gat, ad_gat, as_x, ad_x,
        es1, ed1, esC, edD, esS, N, NB128);

    // all three GATs in one launch (split-chain GAT1; interleaved dual waves)
    gather_all_kernel<<<(2 * N * 64 + 255) / 256, blk, 0, stream>>>(
        off3, cnt3, srcs3, es1, ed1, esC, edD, esS, ab_gat, ab_x,
        Wh1, WhC, WhS3, xb, hmixb, N);

    // fused GRU
    gru_fused_kernel<<<dim3(4, NB128), blk512, 0, stream>>>(
        xb, hmixb, Bihr, Bhhr, b_ih, b_hh, (float*)d_out, N);
}